// Round 7
// baseline (212.530 us; speedup 1.0000x reference)
//
#include <hip/hip_runtime.h>

#define BB 2
#define CC 64
#define HH 128
#define WW 128
#define NN (HH*WW)          // 16384 queries per batch
#define MM ((HH/2)*(WW/2))  // 4096 keys per batch
#define CV 32
#define LOG2E 1.44269504088896f

typedef __attribute__((ext_vector_type(8))) short bf16x8;
typedef __attribute__((ext_vector_type(4))) float f32x4;
typedef unsigned int uint32;

union U8 { bf16x8 v; uint32 u[4]; };

__device__ __forceinline__ short f2bf(float f) {
    union { float f; unsigned u; } v; v.f = f;
    unsigned u = v.u + 0x7fffu + ((v.u >> 16) & 1u);   // RNE
    return (short)(u >> 16);
}
__device__ __forceinline__ uint32 pack2bf(float lo, float hi) {
    return (uint32)(unsigned short)f2bf(lo) | ((uint32)(unsigned short)f2bf(hi) << 16);
}
// 1-instr truncation pack via v_perm_b32; downward bias cancels in P/l ratio
__device__ __forceinline__ uint32 packperm(float lo, float hi) {
    union { float f; uint32 u; } a, b; a.f = lo; b.f = hi;
    return __builtin_amdgcn_perm(b.u, a.u, 0x07060302u);
}
// async global->LDS DMA, 16B/lane; LDS dst = wave-uniform base + lane*16
__device__ __forceinline__ void gl_lds16(const short* g, short* l) {
    __builtin_amdgcn_global_load_lds(
        (const __attribute__((address_space(1))) void*)g,
        (__attribute__((address_space(3))) void*)l, 16, 0, 0);
}

// ---------------------------------------------------------------------------
// Kernel 1 = R0's proj, byte-exact. Measured (R4 dup-probe): 4.7us.
// ---------------------------------------------------------------------------
__global__ __launch_bounds__(256, 4) void proj_kernel(
    const float* __restrict__ x, const float* __restrict__ wt,
    const float* __restrict__ wp, const float* __restrict__ wg,
    short* __restrict__ Qb, short* __restrict__ Kb, short* __restrict__ Vt)
{
    __shared__ float plds[8192];
    __shared__ float phi_lds[512];
    int tid = threadIdx.x;
    int px = tid & 63, part = tid >> 6;
    int sb = blockIdx.x >> 2, cq = blockIdx.x & 3;
    int b = blockIdx.y, z = blockIdx.z;
    int row = px >> 5, col = cq*32 + (px & 31);
    int n = (2*sb + row)*WW + col;
    int wbase = __builtin_amdgcn_readfirstlane(part*16);

    float xv[16];
    #pragma unroll
    for (int i = 0; i < 16; ++i)
        xv[i] = x[((b*CC + part*16 + i) << 14) + n];

    if (z == 0) {
        float po[16];
        #pragma unroll
        for (int o = 0; o < 8; ++o) {
            float a = 0.f;
            #pragma unroll
            for (int i = 0; i < 16; ++i) a += wt[o*64 + wbase + i]*xv[i];
            po[o] = a;
        }
        #pragma unroll
        for (int o = 0; o < 8; ++o) {
            float a = 0.f;
            #pragma unroll
            for (int i = 0; i < 16; ++i) a += wp[o*64 + wbase + i]*xv[i];
            po[8+o] = a;
        }
        #pragma unroll
        for (int o = 0; o < 16; ++o) plds[(o*4 + part)*64 + px] = po[o];
        __syncthreads();
        int og = tid >> 6;
        float sm[4];
        #pragma unroll
        for (int j = 0; j < 4; ++j) {
            int o = og*4 + j;
            sm[j] = (plds[(o*4+0)*64+px] + plds[(o*4+1)*64+px])
                  + (plds[(o*4+2)*64+px] + plds[(o*4+3)*64+px]);
        }
        if (og < 2) {
            uint2 val;
            val.x = pack2bf(sm[0]*LOG2E, sm[1]*LOG2E);
            val.y = pack2bf(sm[2]*LOG2E, sm[3]*LOG2E);
            ((uint2*)Qb)[(b*NN + n)*2 + og] = val;
        } else {
            #pragma unroll
            for (int j = 0; j < 4; ++j)
                phi_lds[((og-2)*4 + j)*64 + px] = sm[j];
        }
        __syncthreads();
        if (tid < 128) {
            int mm = tid & 15, ch = tid >> 4;
            int p00 = 2*mm, p01 = p00+1, p10 = 32+2*mm, p11 = p10+1;
            float mx = fmaxf(fmaxf(phi_lds[ch*64+p00], phi_lds[ch*64+p01]),
                             fmaxf(phi_lds[ch*64+p10], phi_lds[ch*64+p11]));
            int m = sb*64 + cq*16 + mm;
            Kb[(b*MM + m)*8 + ch] = f2bf(mx);
        }
    } else {
        float po[32];
        #pragma unroll
        for (int o = 0; o < 32; ++o) {
            float a = 0.f;
            #pragma unroll
            for (int i = 0; i < 16; ++i) a += wg[o*64 + wbase + i]*xv[i];
            po[o] = a;
        }
        #pragma unroll
        for (int o = 0; o < 32; ++o) plds[(o*4 + part)*64 + px] = po[o];
        __syncthreads();
        int og = tid >> 6;
        float sm[8];
        #pragma unroll
        for (int j = 0; j < 8; ++j) {
            int o = og*8 + j;
            sm[j] = (plds[(o*4+0)*64+px] + plds[(o*4+1)*64+px])
                  + (plds[(o*4+2)*64+px] + plds[(o*4+3)*64+px]);
        }
        __syncthreads();
        #pragma unroll
        for (int j = 0; j < 8; ++j)
            plds[(og*8 + j)*64 + px] = sm[j];
        __syncthreads();
        int mm = tid & 15, chb = tid >> 4;
        int p00 = 2*mm, p01 = p00+1, p10 = 32+2*mm, p11 = p10+1;
        int w64 = cq*16 + mm;
        int hh = w64 >> 5, w = w64 & 31;
        int slot = ((w >> 2) & 3)*8 + (w & 3) + ((w >> 4) << 2);
        int pos64 = hh*32 + slot;
        #pragma unroll
        for (int j = 0; j < 2; ++j) {
            int ch = chb*2 + j;
            float mx = fmaxf(fmaxf(plds[ch*64+p00], plds[ch*64+p01]),
                             fmaxf(plds[ch*64+p10], plds[ch*64+p11]));
            int colv = (pos64 >> 3) ^ (ch & 7);
            Vt[(b*CV + ch)*MM + sb*64 + colv*8 + (pos64 & 7)] = f2bf(mx);
        }
    }
}

// ---------------------------------------------------------------------------
// Kernel 2 = R6's barrier-free attn, COUNTER-PROBE round: entire body wrapped
// in rep x4 (idempotent -- each rep re-stages, re-accumulates, rewrites the
// same out). One dispatch ~95us > the 42us fill cutoff -> attn finally
// surfaces in top-5 with VGPR_Count / Occupancy / VALUBusy / MfmaUtil /
// LDS_BANK_CONFLICT / FETCH_SIZE. Arithmetic per rep byte-identical to R6.
// ---------------------------------------------------------------------------
__global__ __launch_bounds__(256, 4) void attn_kernel(
    const short* __restrict__ Qb, const short* __restrict__ Kb,
    const short* __restrict__ Vt, const float* __restrict__ x,
    const float* __restrict__ wo, const float* __restrict__ gamma,
    float* __restrict__ out)
{
    __shared__ short ldsK[2][4][512];    // 8KB  [buf][wave][64key x 8ch]
    __shared__ short ldsV[2][4][2048];   // 32KB [buf][wave][32ch x 64key swz]
    int tid = threadIdx.x;
    int qtr = tid >> 6, lane = tid & 63;
    int quad = lane >> 4, c15 = lane & 15, sw = c15 & 7;
    int blk = blockIdx.x;
    int b = blk >> 9;
    int q0 = (blk & 511)*32;             // tiles q0, q0+16

    const f32x4 zero4 = {0.f, 0.f, 0.f, 0.f};
    bf16x8 zero8 = (bf16x8)0;
    U8 ones; ones.u[0] = ones.u[1] = ones.u[2] = ones.u[3] = 0x3F803F80u;

    bf16x8 bq0 = (quad == 0) ? ((const bf16x8*)Qb)[b*NN + q0 + c15]      : zero8;
    bf16x8 bq1 = (quad == 0) ? ((const bf16x8*)Qb)[b*NN + q0 + 16 + c15] : zero8;

    // per-wave private DMA sources (this wave's 1024-key quarter, ALL 32 ch)
    const short* ksrc  = Kb + (size_t)b*MM*8 + (qtr*1024 + lane)*8;
    const short* vsrcA = Vt + ((size_t)(b*CV + (lane >> 3)))*MM
                       + qtr*1024 + (lane & 7)*8;       // ch 0..7
    const short* vsrcB = vsrcA + 8*MM;                  // ch 8..15
    const short* vsrcC = vsrcA + 16*MM;                 // ch 16..23
    const short* vsrcD = vsrcA + 24*MM;                 // ch 24..31
    short* kd0 = &ldsK[0][qtr][lane*8];
    short* kd1 = &ldsK[1][qtr][lane*8];
    short* vd0 = &ldsV[0][qtr][lane*8];
    short* vd1 = &ldsV[1][qtr][lane*8];

    for (int rep = 0; rep < 4; ++rep) {

    {   // prologue: stage 0 into buf 0 (5 DMAs)
        gl_lds16(vsrcA, vd0);
        gl_lds16(vsrcB, vd0 + 512);
        gl_lds16(vsrcC, vd0 + 1024);
        gl_lds16(vsrcD, vd0 + 1536);
        gl_lds16(ksrc, kd0);
    }

    f32x4 D0A = zero4, D1A = zero4, DlA = zero4;
    f32x4 D0B = zero4, D1B = zero4, DlB = zero4;

    for (int sc = 0; sc < 16; ++sc) {
        if (sc < 15) {
            int scn = sc + 1;
            short* vd = (scn & 1) ? vd1 : vd0;
            short* kd = (scn & 1) ? kd1 : kd0;
            gl_lds16(vsrcA + scn*64, vd);
            gl_lds16(vsrcB + scn*64, vd + 512);
            gl_lds16(vsrcC + scn*64, vd + 1024);
            gl_lds16(vsrcD + scn*64, vd + 1536);
            gl_lds16(ksrc + scn*512, kd);
            // own outstanding: 5(sc) + 5(sc+1); wait until only the 5 just
            // issued remain -> stage sc landed (vmcnt retires in order)
            asm volatile("s_waitcnt vmcnt(5)" ::: "memory");
        } else {
            asm volatile("s_waitcnt vmcnt(0)" ::: "memory");   // drain last stage
        }
        __builtin_amdgcn_sched_barrier(0);

        const short* bk = (sc & 1) ? &ldsK[1][qtr][0] : &ldsK[0][qtr][0];
        const short* bv = (sc & 1) ? &ldsV[1][qtr][0] : &ldsV[0][qtr][0];
        #pragma unroll
        for (int h = 0; h < 2; ++h) {
            bf16x8 kf0 = *(const bf16x8*)(bk + (h*32 + c15)*8);
            bf16x8 kf1 = *(const bf16x8*)(bk + (h*32 + 16 + c15)*8);
            int col8 = ((h*4 + quad) ^ sw)*8;
            bf16x8 a0 = *(const bf16x8*)(bv + c15*64 + col8);
            bf16x8 a1 = *(const bf16x8*)(bv + (16 + c15)*64 + col8);
            f32x4 s0A = __builtin_amdgcn_mfma_f32_16x16x32_bf16(kf0, bq0, zero4, 0, 0, 0);
            f32x4 s1A = __builtin_amdgcn_mfma_f32_16x16x32_bf16(kf1, bq0, zero4, 0, 0, 0);
            f32x4 s0B = __builtin_amdgcn_mfma_f32_16x16x32_bf16(kf0, bq1, zero4, 0, 0, 0);
            f32x4 s1B = __builtin_amdgcn_mfma_f32_16x16x32_bf16(kf1, bq1, zero4, 0, 0, 0);
            U8 bpA, bpB;
            bpA.u[0] = packperm(__builtin_amdgcn_exp2f(s0A[0]), __builtin_amdgcn_exp2f(s0A[1]));
            bpA.u[1] = packperm(__builtin_amdgcn_exp2f(s0A[2]), __builtin_amdgcn_exp2f(s0A[3]));
            bpA.u[2] = packperm(__builtin_amdgcn_exp2f(s1A[0]), __builtin_amdgcn_exp2f(s1A[1]));
            bpA.u[3] = packperm(__builtin_amdgcn_exp2f(s1A[2]), __builtin_amdgcn_exp2f(s1A[3]));
            bpB.u[0] = packperm(__builtin_amdgcn_exp2f(s0B[0]), __builtin_amdgcn_exp2f(s0B[1]));
            bpB.u[1] = packperm(__builtin_amdgcn_exp2f(s0B[2]), __builtin_amdgcn_exp2f(s0B[3]));
            bpB.u[2] = packperm(__builtin_amdgcn_exp2f(s1B[0]), __builtin_amdgcn_exp2f(s1B[1]));
            bpB.u[3] = packperm(__builtin_amdgcn_exp2f(s1B[2]), __builtin_amdgcn_exp2f(s1B[3]));
            D0A = __builtin_amdgcn_mfma_f32_16x16x32_bf16(a0, bpA.v, D0A, 0, 0, 0);
            D1A = __builtin_amdgcn_mfma_f32_16x16x32_bf16(a1, bpA.v, D1A, 0, 0, 0);
            DlA = __builtin_amdgcn_mfma_f32_16x16x32_bf16(ones.v, bpA.v, DlA, 0, 0, 0);
            D0B = __builtin_amdgcn_mfma_f32_16x16x32_bf16(a0, bpB.v, D0B, 0, 0, 0);
            D1B = __builtin_amdgcn_mfma_f32_16x16x32_bf16(a1, bpB.v, D1B, 0, 0, 0);
            DlB = __builtin_amdgcn_mfma_f32_16x16x32_bf16(ones.v, bpB.v, DlB, 0, 0, 0);
        }
    }

    // combine 4 quarter partials; comb aliased onto the writing wave's OWN
    // (drained) ldsV regions: tile A -> ldsV[0][r], tile B -> ldsV[1][r].
    #pragma unroll
    for (int r = 1; r < 4; ++r) {
        if (qtr == r) {
            float* cA = (float*)&ldsV[0][r][0] + lane*9;
            cA[0]=D0A[0]; cA[1]=D0A[1]; cA[2]=D0A[2]; cA[3]=D0A[3];
            cA[4]=D1A[0]; cA[5]=D1A[1]; cA[6]=D1A[2]; cA[7]=D1A[3];
            cA[8]=DlA[0];
            float* cB = (float*)&ldsV[1][r][0] + lane*9;
            cB[0]=D0B[0]; cB[1]=D0B[1]; cB[2]=D0B[2]; cB[3]=D0B[3];
            cB[4]=D1B[0]; cB[5]=D1B[1]; cB[6]=D1B[2]; cB[7]=D1B[3];
            cB[8]=DlB[0];
        }
        __syncthreads();
        if (qtr == 0) {
            const float* cA = (const float*)&ldsV[0][r][0] + lane*9;
            D0A[0]+=cA[0]; D0A[1]+=cA[1]; D0A[2]+=cA[2]; D0A[3]+=cA[3];
            D1A[0]+=cA[4]; D1A[1]+=cA[5]; D1A[2]+=cA[6]; D1A[3]+=cA[7];
            DlA[0]+=cA[8];
            const float* cB = (const float*)&ldsV[1][r][0] + lane*9;
            D0B[0]+=cB[0]; D0B[1]+=cB[1]; D0B[2]+=cB[2]; D0B[3]+=cB[3];
            D1B[0]+=cB[4]; D1B[1]+=cB[5]; D1B[2]+=cB[6]; D1B[3]+=cB[7];
            DlB[0]+=cB[8];
        }
        __syncthreads();
    }

    if (qtr == 0) {
        float rlA = 1.0f / DlA[0];
        float rlB = 1.0f / DlB[0];
        U8 ByA, ByB;
        ByA.u[0] = pack2bf(D0A[0]*rlA, D0A[1]*rlA); ByA.u[1] = pack2bf(D0A[2]*rlA, D0A[3]*rlA);
        ByA.u[2] = pack2bf(D1A[0]*rlA, D1A[1]*rlA); ByA.u[3] = pack2bf(D1A[2]*rlA, D1A[3]*rlA);
        ByB.u[0] = pack2bf(D0B[0]*rlB, D0B[1]*rlB); ByB.u[1] = pack2bf(D0B[2]*rlB, D0B[3]*rlB);
        ByB.u[2] = pack2bf(D1B[0]*rlB, D1B[1]*rlB); ByB.u[3] = pack2bf(D1B[2]*rlB, D1B[3]*rlB);

        float gam = gamma[0];
        #pragma unroll
        for (int t = 0; t < 4; ++t) {
            int co = t*16 + c15;
            float4 wlo = *(const float4*)(wo + co*32 + quad*4);
            float4 whi = *(const float4*)(wo + co*32 + 16 + quad*4);
            U8 aw;
            aw.u[0] = pack2bf(wlo.x, wlo.y); aw.u[1] = pack2bf(wlo.z, wlo.w);
            aw.u[2] = pack2bf(whi.x, whi.y); aw.u[3] = pack2bf(whi.z, whi.w);
            f32x4 oA = __builtin_amdgcn_mfma_f32_16x16x32_bf16(aw.v, ByA.v, zero4, 0, 0, 0);
            f32x4 oB = __builtin_amdgcn_mfma_f32_16x16x32_bf16(aw.v, ByB.v, zero4, 0, 0, 0);
            #pragma unroll
            for (int r2 = 0; r2 < 4; ++r2) {
                int co_r = t*16 + quad*4 + r2;
                int base = ((b*CC + co_r) << 14) + q0 + c15;
                out[base]      = x[base]      + gam*oA[r2];
                out[base + 16] = x[base + 16] + gam*oB[r2];
            }
        }
    }
    __syncthreads();     // all waves re-converge before next rep re-stages LDS

    }   // rep
}

// ---------------------------------------------------------------------------
// Workspace: Qb 512K @ 0, Kb 128K @ 524288, Vt 512K @ 655360.
// ---------------------------------------------------------------------------
extern "C" void kernel_launch(void* const* d_in, const int* in_sizes, int n_in,
                              void* d_out, int out_size, void* d_ws, size_t ws_size,
                              hipStream_t stream) {
    const float* x     = (const float*)d_in[0];
    const float* wt    = (const float*)d_in[1];
    const float* wp    = (const float*)d_in[2];
    const float* wg    = (const float*)d_in[3];
    const float* wo    = (const float*)d_in[4];
    const float* gamma = (const float*)d_in[5];
    float* out = (float*)d_out;

    char* ws = (char*)d_ws;
    short* Qb = (short*)(ws);
    short* Kb = (short*)(ws + 524288);
    short* Vt = (short*)(ws + 655360);

    dim3 g1(256, BB, 2);
    proj_kernel<<<g1, 256, 0, stream>>>(x, wt, wp, wg, Qb, Kb, Vt);
    attn_kernel<<<BB*NN/32, 256, 0, stream>>>(Qb, Kb, Vt, x, wo, gamma, out);
}

// Round 8
// 112.066 us; speedup vs baseline: 1.8965x; 1.8965x over previous
//
#include <hip/hip_runtime.h>

#define BB 2
#define CC 64
#define HH 128
#define WW 128
#define NN (HH*WW)          // 16384 queries per batch
#define MM ((HH/2)*(WW/2))  // 4096 keys per batch
#define CV 32
#define LOG2E 1.44269504088896f

typedef __attribute__((ext_vector_type(8))) short bf16x8;
typedef __attribute__((ext_vector_type(4))) float f32x4;
typedef unsigned int uint32;

union U8 { bf16x8 v; uint32 u[4]; };

__device__ __forceinline__ short f2bf(float f) {
    union { float f; unsigned u; } v; v.f = f;
    unsigned u = v.u + 0x7fffu + ((v.u >> 16) & 1u);   // RNE
    return (short)(u >> 16);
}
__device__ __forceinline__ uint32 pack2bf(float lo, float hi) {
    return (uint32)(unsigned short)f2bf(lo) | ((uint32)(unsigned short)f2bf(hi) << 16);
}
// 1-instr truncation pack via v_perm_b32; downward bias cancels in P/l ratio
__device__ __forceinline__ uint32 packperm(float lo, float hi) {
    union { float f; uint32 u; } a, b; a.f = lo; b.f = hi;
    return __builtin_amdgcn_perm(b.u, a.u, 0x07060302u);
}
// async global->LDS DMA, 16B/lane; LDS dst = wave-uniform base + lane*16
__device__ __forceinline__ void gl_lds16(const short* g, short* l) {
    __builtin_amdgcn_global_load_lds(
        (const __attribute__((address_space(1))) void*)g,
        (__attribute__((address_space(3))) void*)l, 16, 0, 0);
}

// ---------------------------------------------------------------------------
// Kernel 1 = R0's proj (4.7us measured), ONE change: Vt store drops the octet
// XOR swizzle (colv) -- attn now stages V in octet-major LDS layout which is
// bank-conflict-free without it. Vt = [ch][sb*64 + pos64] (pos64 keeps the
// key permutation that encodes MFMA fragment order -- arithmetic unchanged).
// ---------------------------------------------------------------------------
__global__ __launch_bounds__(256, 4) void proj_kernel(
    const float* __restrict__ x, const float* __restrict__ wt,
    const float* __restrict__ wp, const float* __restrict__ wg,
    short* __restrict__ Qb, short* __restrict__ Kb, short* __restrict__ Vt)
{
    __shared__ float plds[8192];
    __shared__ float phi_lds[512];
    int tid = threadIdx.x;
    int px = tid & 63, part = tid >> 6;
    int sb = blockIdx.x >> 2, cq = blockIdx.x & 3;
    int b = blockIdx.y, z = blockIdx.z;
    int row = px >> 5, col = cq*32 + (px & 31);
    int n = (2*sb + row)*WW + col;
    int wbase = __builtin_amdgcn_readfirstlane(part*16);

    float xv[16];
    #pragma unroll
    for (int i = 0; i < 16; ++i)
        xv[i] = x[((b*CC + part*16 + i) << 14) + n];

    if (z == 0) {
        float po[16];
        #pragma unroll
        for (int o = 0; o < 8; ++o) {
            float a = 0.f;
            #pragma unroll
            for (int i = 0; i < 16; ++i) a += wt[o*64 + wbase + i]*xv[i];
            po[o] = a;
        }
        #pragma unroll
        for (int o = 0; o < 8; ++o) {
            float a = 0.f;
            #pragma unroll
            for (int i = 0; i < 16; ++i) a += wp[o*64 + wbase + i]*xv[i];
            po[8+o] = a;
        }
        #pragma unroll
        for (int o = 0; o < 16; ++o) plds[(o*4 + part)*64 + px] = po[o];
        __syncthreads();
        int og = tid >> 6;
        float sm[4];
        #pragma unroll
        for (int j = 0; j < 4; ++j) {
            int o = og*4 + j;
            sm[j] = (plds[(o*4+0)*64+px] + plds[(o*4+1)*64+px])
                  + (plds[(o*4+2)*64+px] + plds[(o*4+3)*64+px]);
        }
        if (og < 2) {
            uint2 val;
            val.x = pack2bf(sm[0]*LOG2E, sm[1]*LOG2E);
            val.y = pack2bf(sm[2]*LOG2E, sm[3]*LOG2E);
            ((uint2*)Qb)[(b*NN + n)*2 + og] = val;
        } else {
            #pragma unroll
            for (int j = 0; j < 4; ++j)
                phi_lds[((og-2)*4 + j)*64 + px] = sm[j];
        }
        __syncthreads();
        if (tid < 128) {
            int mm = tid & 15, ch = tid >> 4;
            int p00 = 2*mm, p01 = p00+1, p10 = 32+2*mm, p11 = p10+1;
            float mx = fmaxf(fmaxf(phi_lds[ch*64+p00], phi_lds[ch*64+p01]),
                             fmaxf(phi_lds[ch*64+p10], phi_lds[ch*64+p11]));
            int m = sb*64 + cq*16 + mm;
            Kb[(b*MM + m)*8 + ch] = f2bf(mx);
        }
    } else {
        float po[32];
        #pragma unroll
        for (int o = 0; o < 32; ++o) {
            float a = 0.f;
            #pragma unroll
            for (int i = 0; i < 16; ++i) a += wg[o*64 + wbase + i]*xv[i];
            po[o] = a;
        }
        #pragma unroll
        for (int o = 0; o < 32; ++o) plds[(o*4 + part)*64 + px] = po[o];
        __syncthreads();
        int og = tid >> 6;
        float sm[8];
        #pragma unroll
        for (int j = 0; j < 8; ++j) {
            int o = og*8 + j;
            sm[j] = (plds[(o*4+0)*64+px] + plds[(o*4+1)*64+px])
                  + (plds[(o*4+2)*64+px] + plds[(o*4+3)*64+px]);
        }
        __syncthreads();
        #pragma unroll
        for (int j = 0; j < 8; ++j)
            plds[(og*8 + j)*64 + px] = sm[j];
        __syncthreads();
        int mm = tid & 15, chb = tid >> 4;
        int p00 = 2*mm, p01 = p00+1, p10 = 32+2*mm, p11 = p10+1;
        int w64 = cq*16 + mm;
        int hh = w64 >> 5, w = w64 & 31;
        int slot = ((w >> 2) & 3)*8 + (w & 3) + ((w >> 4) << 2);
        int pos64 = hh*32 + slot;
        #pragma unroll
        for (int j = 0; j < 2; ++j) {
            int ch = chb*2 + j;
            float mx = fmaxf(fmaxf(plds[ch*64+p00], plds[ch*64+p01]),
                             fmaxf(plds[ch*64+p10], plds[ch*64+p11]));
            Vt[(b*CV + ch)*MM + sb*64 + pos64] = f2bf(mx);   // no XOR swizzle
        }
    }
}

// ---------------------------------------------------------------------------
// Kernel 2: barrier-free per-wave staging with DEPTH-2 prefetch at 32-key
// granularity. R7 counters: Occ 41%, VALU 42%, MFMA 25%, conflicts 0 ->
// ~58% of issue slots stalled; 1-stage-ahead DMA (~300cy hide) < L2/HBM
// latency (~400-900cy after the poison fill). Now: V = 4-deep ring of 2KB
// sub-stage buffers, DMA issued TWO sub-stages (~600-1100cy) ahead; K dbuf
// at 64-key pairs issued 2-3 sub-stages ahead. LDS 10KB/wave (unchanged
// envelope). V staged octet-major -> conflict-free without XOR swizzle.
// vmcnt proof (queue oldest->newest, issue order V,V[,K] per sub-stage):
//  need at t: V(t) [issued t-2] and K(t>>1) [issued at even t-2/t-3, after
//  V(t) when same sub-stage]. Newer-than-needed = V(t+1)x2 + V(t+2)x2 +
//  exactly one K = 5 for t<=29; t=30 -> 2; t=31 -> 0.
// ---------------------------------------------------------------------------
__global__ __launch_bounds__(256, 4) void attn_kernel(
    const short* __restrict__ Qb, const short* __restrict__ Kb,
    const short* __restrict__ Vt, const float* __restrict__ x,
    const float* __restrict__ wo, const float* __restrict__ gamma,
    float* __restrict__ out)
{
    // per-wave 5120 shorts: K[2][512] @0 | V[4][1024] @1024 (oct-major 32key)
    __shared__ short stage[4][5120];     // 40KB total
    int tid = threadIdx.x;
    int qtr = tid >> 6, lane = tid & 63;
    int quad = lane >> 4, c15 = lane & 15;
    int blk = blockIdx.x;
    int b = blk >> 9;
    int q0 = (blk & 511)*32;             // tiles q0, q0+16

    const f32x4 zero4 = {0.f, 0.f, 0.f, 0.f};
    bf16x8 zero8 = (bf16x8)0;
    U8 ones; ones.u[0] = ones.u[1] = ones.u[2] = ones.u[3] = 0x3F803F80u;

    bf16x8 bq0 = (quad == 0) ? ((const bf16x8*)Qb)[b*NN + q0 + c15]      : zero8;
    bf16x8 bq1 = (quad == 0) ? ((const bf16x8*)Qb)[b*NN + q0 + 16 + c15] : zero8;

    short* sw_ = &stage[qtr][0];
    // K src: lane -> key (within 64-pair), 8ch contiguous
    const short* ksrc = Kb + (size_t)b*MM*8 + (qtr*1024 + lane)*8;
    // V src oct-major: lane -> ch = lane&15, octet = lane>>4
    const short* vsA  = Vt + ((size_t)(b*CV + (lane & 15)))*MM + qtr*1024 + (lane >> 4)*8;
    const short* vsB  = vsA + 16*MM;                 // ch 16..31
    short* kdst = sw_ + lane*8;                      // + KB*512
    short* vdst = sw_ + 1024 + lane*8;               // + VB*1024 (+512 for B)

    // prologue: V(0), K(0), V(1)   [queue: V0a,V0b,K0,V1a,V1b]
    gl_lds16(vsA,      vdst);
    gl_lds16(vsB,      vdst + 512);
    gl_lds16(ksrc,     kdst);
    gl_lds16(vsA + 32, vdst + 1024);
    gl_lds16(vsB + 32, vdst + 1536);

    f32x4 D0A = zero4, D1A = zero4, DlA = zero4;
    f32x4 D0B = zero4, D1B = zero4, DlB = zero4;

#define SUBSTAGE(T, VB, KB, H, IV, IK, WN)                                      \
    {                                                                           \
        if (IV) {                                                               \
            gl_lds16(vsA + ((T)+2)*32, vdst + ((((VB)+2)&3))*1024);             \
            gl_lds16(vsB + ((T)+2)*32, vdst + ((((VB)+2)&3))*1024 + 512);       \
        }                                                                       \
        if (IK) {                                                               \
            gl_lds16(ksrc + ((((T)>>1)+1))*512, kdst + ((((((T)>>1)+1))&1))*512);\
        }                                                                       \
        asm volatile("s_waitcnt vmcnt(" #WN ")" ::: "memory");                  \
        __builtin_amdgcn_sched_barrier(0);                                      \
        const short* bk = sw_ + (KB)*512;                                       \
        const short* bv = sw_ + 1024 + (VB)*1024;                               \
        bf16x8 kf0 = *(const bf16x8*)(bk + ((H)*32 + c15)*8);                   \
        bf16x8 kf1 = *(const bf16x8*)(bk + ((H)*32 + 16 + c15)*8);              \
        bf16x8 a0  = *(const bf16x8*)(bv + quad*128 + c15*8);                   \
        bf16x8 a1  = *(const bf16x8*)(bv + 512 + quad*128 + c15*8);             \
        f32x4 s0A = __builtin_amdgcn_mfma_f32_16x16x32_bf16(kf0, bq0, zero4, 0, 0, 0); \
        f32x4 s1A = __builtin_amdgcn_mfma_f32_16x16x32_bf16(kf1, bq0, zero4, 0, 0, 0); \
        f32x4 s0B = __builtin_amdgcn_mfma_f32_16x16x32_bf16(kf0, bq1, zero4, 0, 0, 0); \
        f32x4 s1B = __builtin_amdgcn_mfma_f32_16x16x32_bf16(kf1, bq1, zero4, 0, 0, 0); \
        U8 bpA, bpB;                                                            \
        bpA.u[0] = packperm(__builtin_amdgcn_exp2f(s0A[0]), __builtin_amdgcn_exp2f(s0A[1])); \
        bpA.u[1] = packperm(__builtin_amdgcn_exp2f(s0A[2]), __builtin_amdgcn_exp2f(s0A[3])); \
        bpA.u[2] = packperm(__builtin_amdgcn_exp2f(s1A[0]), __builtin_amdgcn_exp2f(s1A[1])); \
        bpA.u[3] = packperm(__builtin_amdgcn_exp2f(s1A[2]), __builtin_amdgcn_exp2f(s1A[3])); \
        bpB.u[0] = packperm(__builtin_amdgcn_exp2f(s0B[0]), __builtin_amdgcn_exp2f(s0B[1])); \
        bpB.u[1] = packperm(__builtin_amdgcn_exp2f(s0B[2]), __builtin_amdgcn_exp2f(s0B[3])); \
        bpB.u[2] = packperm(__builtin_amdgcn_exp2f(s1B[0]), __builtin_amdgcn_exp2f(s1B[1])); \
        bpB.u[3] = packperm(__builtin_amdgcn_exp2f(s1B[2]), __builtin_amdgcn_exp2f(s1B[3])); \
        D0A = __builtin_amdgcn_mfma_f32_16x16x32_bf16(a0, bpA.v, D0A, 0, 0, 0); \
        D1A = __builtin_amdgcn_mfma_f32_16x16x32_bf16(a1, bpA.v, D1A, 0, 0, 0); \
        DlA = __builtin_amdgcn_mfma_f32_16x16x32_bf16(ones.v, bpA.v, DlA, 0, 0, 0); \
        D0B = __builtin_amdgcn_mfma_f32_16x16x32_bf16(a0, bpB.v, D0B, 0, 0, 0); \
        D1B = __builtin_amdgcn_mfma_f32_16x16x32_bf16(a1, bpB.v, D1B, 0, 0, 0); \
        DlB = __builtin_amdgcn_mfma_f32_16x16x32_bf16(ones.v, bpB.v, DlB, 0, 0, 0); \
    }

    #pragma unroll 1
    for (int tp = 0; tp < 7; ++tp) {
        int T0 = 4*tp;
        SUBSTAGE(T0+0, 0, 0, 0, 1, 1, 5)
        SUBSTAGE(T0+1, 1, 0, 1, 1, 0, 5)
        SUBSTAGE(T0+2, 2, 1, 0, 1, 1, 5)
        SUBSTAGE(T0+3, 3, 1, 1, 1, 0, 5)
    }
    // tail: t = 28..31 (V30,V31 + K15 issued at t=28/29; then drain)
    SUBSTAGE(28, 0, 0, 0, 1, 1, 5)
    SUBSTAGE(29, 1, 0, 1, 1, 0, 5)
    SUBSTAGE(30, 2, 1, 0, 0, 0, 2)
    SUBSTAGE(31, 3, 1, 1, 0, 0, 0)
#undef SUBSTAGE

    // combine: waves 1..3 write partials into their OWN drained stage region
    // (private, disjoint); one barrier; wave 0 accumulates all three.
    if (qtr != 0) {
        float* cb = (float*)sw_;
        float* cA = cb + lane*9;
        cA[0]=D0A[0]; cA[1]=D0A[1]; cA[2]=D0A[2]; cA[3]=D0A[3];
        cA[4]=D1A[0]; cA[5]=D1A[1]; cA[6]=D1A[2]; cA[7]=D1A[3];
        cA[8]=DlA[0];
        float* cB = cb + 576 + lane*9;
        cB[0]=D0B[0]; cB[1]=D0B[1]; cB[2]=D0B[2]; cB[3]=D0B[3];
        cB[4]=D1B[0]; cB[5]=D1B[1]; cB[6]=D1B[2]; cB[7]=D1B[3];
        cB[8]=DlB[0];
    }
    __syncthreads();
    if (qtr != 0) return;        // no barriers past this point

    #pragma unroll
    for (int r = 1; r < 4; ++r) {
        const float* cb = (const float*)&stage[r][0];
        const float* cA = cb + lane*9;
        D0A[0]+=cA[0]; D0A[1]+=cA[1]; D0A[2]+=cA[2]; D0A[3]+=cA[3];
        D1A[0]+=cA[4]; D1A[1]+=cA[5]; D1A[2]+=cA[6]; D1A[3]+=cA[7];
        DlA[0]+=cA[8];
        const float* cB = cb + 576 + lane*9;
        D0B[0]+=cB[0]; D0B[1]+=cB[1]; D0B[2]+=cB[2]; D0B[3]+=cB[3];
        D1B[0]+=cB[4]; D1B[1]+=cB[5]; D1B[2]+=cB[6]; D1B[3]+=cB[7];
        DlB[0]+=cB[8];
    }

    float rlA = 1.0f / DlA[0];
    float rlB = 1.0f / DlB[0];
    U8 ByA, ByB;
    ByA.u[0] = pack2bf(D0A[0]*rlA, D0A[1]*rlA); ByA.u[1] = pack2bf(D0A[2]*rlA, D0A[3]*rlA);
    ByA.u[2] = pack2bf(D1A[0]*rlA, D1A[1]*rlA); ByA.u[3] = pack2bf(D1A[2]*rlA, D1A[3]*rlA);
    ByB.u[0] = pack2bf(D0B[0]*rlB, D0B[1]*rlB); ByB.u[1] = pack2bf(D0B[2]*rlB, D0B[3]*rlB);
    ByB.u[2] = pack2bf(D1B[0]*rlB, D1B[1]*rlB); ByB.u[3] = pack2bf(D1B[2]*rlB, D1B[3]*rlB);

    float gam = gamma[0];
    #pragma unroll
    for (int t = 0; t < 4; ++t) {
        int co = t*16 + c15;
        float4 wlo = *(const float4*)(wo + co*32 + quad*4);
        float4 whi = *(const float4*)(wo + co*32 + 16 + quad*4);
        U8 aw;
        aw.u[0] = pack2bf(wlo.x, wlo.y); aw.u[1] = pack2bf(wlo.z, wlo.w);
        aw.u[2] = pack2bf(whi.x, whi.y); aw.u[3] = pack2bf(whi.z, whi.w);
        f32x4 oA = __builtin_amdgcn_mfma_f32_16x16x32_bf16(aw.v, ByA.v, zero4, 0, 0, 0);
        f32x4 oB = __builtin_amdgcn_mfma_f32_16x16x32_bf16(aw.v, ByB.v, zero4, 0, 0, 0);
        #pragma unroll
        for (int r2 = 0; r2 < 4; ++r2) {
            int co_r = t*16 + quad*4 + r2;
            int base = ((b*CC + co_r) << 14) + q0 + c15;
            out[base]      = x[base]      + gam*oA[r2];
            out[base + 16] = x[base + 16] + gam*oB[r2];
        }
    }
}

// ---------------------------------------------------------------------------
// Workspace: Qb 512K @ 0, Kb 128K @ 524288, Vt 512K @ 655360.
// ---------------------------------------------------------------------------
extern "C" void kernel_launch(void* const* d_in, const int* in_sizes, int n_in,
                              void* d_out, int out_size, void* d_ws, size_t ws_size,
                              hipStream_t stream) {
    const float* x     = (const float*)d_in[0];
    const float* wt    = (const float*)d_in[1];
    const float* wp    = (const float*)d_in[2];
    const float* wg    = (const float*)d_in[3];
    const float* wo    = (const float*)d_in[4];
    const float* gamma = (const float*)d_in[5];
    float* out = (float*)d_out;

    char* ws = (char*)d_ws;
    short* Qb = (short*)(ws);
    short* Kb = (short*)(ws + 524288);
    short* Vt = (short*)(ws + 655360);

    dim3 g1(256, BB, 2);
    proj_kernel<<<g1, 256, 0, stream>>>(x, wt, wp, wg, Qb, Kb, Vt);
    attn_kernel<<<BB*NN/32, 256, 0, stream>>>(Qb, Kb, Vt, x, wo, gamma, out);
}

// Round 9
// 100.531 us; speedup vs baseline: 2.1141x; 1.1147x over previous
//
#include <hip/hip_runtime.h>

#define BB 2
#define CC 64
#define HH 128
#define WW 128
#define NN (HH*WW)          // 16384 queries per batch
#define MM ((HH/2)*(WW/2))  // 4096 keys per batch
#define CV 32
#define LOG2E 1.44269504088896f

typedef __attribute__((ext_vector_type(8))) short bf16x8;
typedef __attribute__((ext_vector_type(4))) float f32x4;
typedef unsigned int uint32;

union U8 { bf16x8 v; uint32 u[4]; };

__device__ __forceinline__ short f2bf(float f) {
    union { float f; unsigned u; } v; v.f = f;
    unsigned u = v.u + 0x7fffu + ((v.u >> 16) & 1u);   // RNE
    return (short)(u >> 16);
}
__device__ __forceinline__ uint32 pack2bf(float lo, float hi) {
    return (uint32)(unsigned short)f2bf(lo) | ((uint32)(unsigned short)f2bf(hi) << 16);
}
// 1-instr truncation pack via v_perm_b32; downward bias cancels in P/l ratio
__device__ __forceinline__ uint32 packperm(float lo, float hi) {
    union { float f; uint32 u; } a, b; a.f = lo; b.f = hi;
    return __builtin_amdgcn_perm(b.u, a.u, 0x07060302u);
}
// async global->LDS DMA, 16B/lane; LDS dst = wave-uniform base + lane*16
__device__ __forceinline__ void gl_lds16(const short* g, short* l) {
    __builtin_amdgcn_global_load_lds(
        (const __attribute__((address_space(1))) void*)g,
        (__attribute__((address_space(3))) void*)l, 16, 0, 0);
}

// ---------------------------------------------------------------------------
// Kernel 1 = R0's proj, byte-exact (XOR swizzle in Vt RESTORED to match the
// R6 attn V layout). Measured 4.7us (R4 dup-probe) -- at its floor.
// ---------------------------------------------------------------------------
__global__ __launch_bounds__(256, 4) void proj_kernel(
    const float* __restrict__ x, const float* __restrict__ wt,
    const float* __restrict__ wp, const float* __restrict__ wg,
    short* __restrict__ Qb, short* __restrict__ Kb, short* __restrict__ Vt)
{
    __shared__ float plds[8192];
    __shared__ float phi_lds[512];
    int tid = threadIdx.x;
    int px = tid & 63, part = tid >> 6;
    int sb = blockIdx.x >> 2, cq = blockIdx.x & 3;
    int b = blockIdx.y, z = blockIdx.z;
    int row = px >> 5, col = cq*32 + (px & 31);
    int n = (2*sb + row)*WW + col;
    int wbase = __builtin_amdgcn_readfirstlane(part*16);

    float xv[16];
    #pragma unroll
    for (int i = 0; i < 16; ++i)
        xv[i] = x[((b*CC + part*16 + i) << 14) + n];

    if (z == 0) {
        float po[16];
        #pragma unroll
        for (int o = 0; o < 8; ++o) {
            float a = 0.f;
            #pragma unroll
            for (int i = 0; i < 16; ++i) a += wt[o*64 + wbase + i]*xv[i];
            po[o] = a;
        }
        #pragma unroll
        for (int o = 0; o < 8; ++o) {
            float a = 0.f;
            #pragma unroll
            for (int i = 0; i < 16; ++i) a += wp[o*64 + wbase + i]*xv[i];
            po[8+o] = a;
        }
        #pragma unroll
        for (int o = 0; o < 16; ++o) plds[(o*4 + part)*64 + px] = po[o];
        __syncthreads();
        int og = tid >> 6;
        float sm[4];
        #pragma unroll
        for (int j = 0; j < 4; ++j) {
            int o = og*4 + j;
            sm[j] = (plds[(o*4+0)*64+px] + plds[(o*4+1)*64+px])
                  + (plds[(o*4+2)*64+px] + plds[(o*4+3)*64+px]);
        }
        if (og < 2) {
            uint2 val;
            val.x = pack2bf(sm[0]*LOG2E, sm[1]*LOG2E);
            val.y = pack2bf(sm[2]*LOG2E, sm[3]*LOG2E);
            ((uint2*)Qb)[(b*NN + n)*2 + og] = val;
        } else {
            #pragma unroll
            for (int j = 0; j < 4; ++j)
                phi_lds[((og-2)*4 + j)*64 + px] = sm[j];
        }
        __syncthreads();
        if (tid < 128) {
            int mm = tid & 15, ch = tid >> 4;
            int p00 = 2*mm, p01 = p00+1, p10 = 32+2*mm, p11 = p10+1;
            float mx = fmaxf(fmaxf(phi_lds[ch*64+p00], phi_lds[ch*64+p01]),
                             fmaxf(phi_lds[ch*64+p10], phi_lds[ch*64+p11]));
            int m = sb*64 + cq*16 + mm;
            Kb[(b*MM + m)*8 + ch] = f2bf(mx);
        }
    } else {
        float po[32];
        #pragma unroll
        for (int o = 0; o < 32; ++o) {
            float a = 0.f;
            #pragma unroll
            for (int i = 0; i < 16; ++i) a += wg[o*64 + wbase + i]*xv[i];
            po[o] = a;
        }
        #pragma unroll
        for (int o = 0; o < 32; ++o) plds[(o*4 + part)*64 + px] = po[o];
        __syncthreads();
        int og = tid >> 6;
        float sm[8];
        #pragma unroll
        for (int j = 0; j < 8; ++j) {
            int o = og*8 + j;
            sm[j] = (plds[(o*4+0)*64+px] + plds[(o*4+1)*64+px])
                  + (plds[(o*4+2)*64+px] + plds[(o*4+3)*64+px]);
        }
        __syncthreads();
        #pragma unroll
        for (int j = 0; j < 8; ++j)
            plds[(og*8 + j)*64 + px] = sm[j];
        __syncthreads();
        int mm = tid & 15, chb = tid >> 4;
        int p00 = 2*mm, p01 = p00+1, p10 = 32+2*mm, p11 = p10+1;
        int w64 = cq*16 + mm;
        int hh = w64 >> 5, w = w64 & 31;
        int slot = ((w >> 2) & 3)*8 + (w & 3) + ((w >> 4) << 2);
        int pos64 = hh*32 + slot;
        #pragma unroll
        for (int j = 0; j < 2; ++j) {
            int ch = chb*2 + j;
            float mx = fmaxf(fmaxf(plds[ch*64+p00], plds[ch*64+p01]),
                             fmaxf(plds[ch*64+p10], plds[ch*64+p11]));
            int colv = (pos64 >> 3) ^ (ch & 7);
            Vt[(b*CV + ch)*MM + sb*64 + colv*8 + (pos64 & 7)] = f2bf(mx);
        }
    }
}

// ---------------------------------------------------------------------------
// Kernel 2 = R6's barrier-free attn (best measured: 23.7us), with ONE lever:
// 64 QUERIES PER WAVE (4 Q-tiles A..D). Each h-body loads kf0/kf1/a0/a1 ONCE
// and runs 4 tiles against them -> the per-stage fixed costs (ds_reads,
// addressing, loop, DMA waits) amortize over 2x work, and total staging
// traffic halves (512 blocks instead of 1024 re-pulling the same K/V from
// L2). DMA schedule, LDS layout, vmcnt(5) logic byte-identical to R6.
// VGPR ~110 (12 acc f32x4 + 4 Q frags) stays in the 65-128 band -> occupancy
// unchanged (LDS-capped 4 blocks/CU). Combine in 2 rounds through the same
// drained-V aliasing.
// ---------------------------------------------------------------------------
__global__ __launch_bounds__(256, 4) void attn_kernel(
    const short* __restrict__ Qb, const short* __restrict__ Kb,
    const short* __restrict__ Vt, const float* __restrict__ x,
    const float* __restrict__ wo, const float* __restrict__ gamma,
    float* __restrict__ out)
{
    __shared__ short ldsK[2][4][512];    // 8KB  [buf][wave][64key x 8ch]
    __shared__ short ldsV[2][4][2048];   // 32KB [buf][wave][32ch x 64key swz]
    int tid = threadIdx.x;
    int qtr = tid >> 6, lane = tid & 63;
    int quad = lane >> 4, c15 = lane & 15, sw = c15 & 7;
    int blk = blockIdx.x;
    int b = blk >> 8;
    int q0 = (blk & 255)*64;             // tiles q0, +16, +32, +48

    const f32x4 zero4 = {0.f, 0.f, 0.f, 0.f};
    bf16x8 zero8 = (bf16x8)0;
    U8 ones; ones.u[0] = ones.u[1] = ones.u[2] = ones.u[3] = 0x3F803F80u;

    bf16x8 bqA = (quad == 0) ? ((const bf16x8*)Qb)[b*NN + q0 + c15]      : zero8;
    bf16x8 bqB = (quad == 0) ? ((const bf16x8*)Qb)[b*NN + q0 + 16 + c15] : zero8;
    bf16x8 bqC = (quad == 0) ? ((const bf16x8*)Qb)[b*NN + q0 + 32 + c15] : zero8;
    bf16x8 bqD = (quad == 0) ? ((const bf16x8*)Qb)[b*NN + q0 + 48 + c15] : zero8;

    // per-wave private DMA sources (this wave's 1024-key quarter, ALL 32 ch)
    const short* ksrc  = Kb + (size_t)b*MM*8 + (qtr*1024 + lane)*8;
    const short* vsrcA = Vt + ((size_t)(b*CV + (lane >> 3)))*MM
                       + qtr*1024 + (lane & 7)*8;       // ch 0..7
    const short* vsrcB = vsrcA + 8*MM;                  // ch 8..15
    const short* vsrcC = vsrcA + 16*MM;                 // ch 16..23
    const short* vsrcD = vsrcA + 24*MM;                 // ch 24..31
    short* kd0 = &ldsK[0][qtr][lane*8];
    short* kd1 = &ldsK[1][qtr][lane*8];
    short* vd0 = &ldsV[0][qtr][lane*8];
    short* vd1 = &ldsV[1][qtr][lane*8];

    {   // prologue: stage 0 into buf 0 (5 DMAs)
        gl_lds16(vsrcA, vd0);
        gl_lds16(vsrcB, vd0 + 512);
        gl_lds16(vsrcC, vd0 + 1024);
        gl_lds16(vsrcD, vd0 + 1536);
        gl_lds16(ksrc, kd0);
    }

    f32x4 D0A = zero4, D1A = zero4, DlA = zero4;
    f32x4 D0B = zero4, D1B = zero4, DlB = zero4;
    f32x4 D0C = zero4, D1C = zero4, DlC = zero4;
    f32x4 D0D = zero4, D1D = zero4, DlD = zero4;

#define TILE(bq, D0, D1, Dl)                                                    \
    {                                                                           \
        f32x4 s0 = __builtin_amdgcn_mfma_f32_16x16x32_bf16(kf0, bq, zero4, 0, 0, 0); \
        f32x4 s1 = __builtin_amdgcn_mfma_f32_16x16x32_bf16(kf1, bq, zero4, 0, 0, 0); \
        U8 bp;                                                                  \
        bp.u[0] = packperm(__builtin_amdgcn_exp2f(s0[0]), __builtin_amdgcn_exp2f(s0[1])); \
        bp.u[1] = packperm(__builtin_amdgcn_exp2f(s0[2]), __builtin_amdgcn_exp2f(s0[3])); \
        bp.u[2] = packperm(__builtin_amdgcn_exp2f(s1[0]), __builtin_amdgcn_exp2f(s1[1])); \
        bp.u[3] = packperm(__builtin_amdgcn_exp2f(s1[2]), __builtin_amdgcn_exp2f(s1[3])); \
        D0 = __builtin_amdgcn_mfma_f32_16x16x32_bf16(a0, bp.v, D0, 0, 0, 0);    \
        D1 = __builtin_amdgcn_mfma_f32_16x16x32_bf16(a1, bp.v, D1, 0, 0, 0);    \
        Dl = __builtin_amdgcn_mfma_f32_16x16x32_bf16(ones.v, bp.v, Dl, 0, 0, 0);\
    }

    for (int sc = 0; sc < 16; ++sc) {
        if (sc < 15) {
            int scn = sc + 1;
            short* vd = (scn & 1) ? vd1 : vd0;
            short* kd = (scn & 1) ? kd1 : kd0;
            gl_lds16(vsrcA + scn*64, vd);
            gl_lds16(vsrcB + scn*64, vd + 512);
            gl_lds16(vsrcC + scn*64, vd + 1024);
            gl_lds16(vsrcD + scn*64, vd + 1536);
            gl_lds16(ksrc + scn*512, kd);
            // own outstanding: 5(sc) + 5(sc+1); wait until only the 5 just
            // issued remain -> stage sc landed (vmcnt retires in order)
            asm volatile("s_waitcnt vmcnt(5)" ::: "memory");
        } else {
            asm volatile("s_waitcnt vmcnt(0)" ::: "memory");   // drain last stage
        }
        __builtin_amdgcn_sched_barrier(0);

        const short* bk = (sc & 1) ? &ldsK[1][qtr][0] : &ldsK[0][qtr][0];
        const short* bv = (sc & 1) ? &ldsV[1][qtr][0] : &ldsV[0][qtr][0];
        #pragma unroll
        for (int h = 0; h < 2; ++h) {
            bf16x8 kf0 = *(const bf16x8*)(bk + (h*32 + c15)*8);
            bf16x8 kf1 = *(const bf16x8*)(bk + (h*32 + 16 + c15)*8);
            int col8 = ((h*4 + quad) ^ sw)*8;
            bf16x8 a0 = *(const bf16x8*)(bv + c15*64 + col8);
            bf16x8 a1 = *(const bf16x8*)(bv + (16 + c15)*64 + col8);
            TILE(bqA, D0A, D1A, DlA)
            TILE(bqB, D0B, D1B, DlB)
            TILE(bqC, D0C, D1C, DlC)
            TILE(bqD, D0D, D1D, DlD)
        }
    }
#undef TILE

    // combine, 2 rounds through each wave's OWN drained ldsV regions
    // (ldsV[0][qtr] and ldsV[1][qtr], 4KB each; 576 floats = 2304B fits).
#define CSTORE(reg0, reg1, regl, base)                                          \
    {   float* c = (float*)(base) + lane*9;                                     \
        c[0]=reg0[0]; c[1]=reg0[1]; c[2]=reg0[2]; c[3]=reg0[3];                 \
        c[4]=reg1[0]; c[5]=reg1[1]; c[6]=reg1[2]; c[7]=reg1[3];                 \
        c[8]=regl[0]; }
#define CLOAD(reg0, reg1, regl, base)                                           \
    {   const float* c = (const float*)(base) + lane*9;                         \
        reg0[0]+=c[0]; reg0[1]+=c[1]; reg0[2]+=c[2]; reg0[3]+=c[3];             \
        reg1[0]+=c[4]; reg1[1]+=c[5]; reg1[2]+=c[6]; reg1[3]+=c[7];             \
        regl[0]+=c[8]; }

    if (qtr != 0) {
        CSTORE(D0A, D1A, DlA, &ldsV[0][qtr][0])
        CSTORE(D0B, D1B, DlB, &ldsV[1][qtr][0])
    }
    __syncthreads();
    if (qtr == 0) {
        #pragma unroll
        for (int r = 1; r < 4; ++r) {
            CLOAD(D0A, D1A, DlA, &ldsV[0][r][0])
            CLOAD(D0B, D1B, DlB, &ldsV[1][r][0])
        }
    }
    __syncthreads();
    if (qtr != 0) {
        CSTORE(D0C, D1C, DlC, &ldsV[0][qtr][0])
        CSTORE(D0D, D1D, DlD, &ldsV[1][qtr][0])
    }
    __syncthreads();
    if (qtr != 0) return;        // no barriers past this point
    #pragma unroll
    for (int r = 1; r < 4; ++r) {
        CLOAD(D0C, D1C, DlC, &ldsV[0][r][0])
        CLOAD(D0D, D1D, DlD, &ldsV[1][r][0])
    }
#undef CSTORE
#undef CLOAD

    float rlA = 1.0f / DlA[0];
    float rlB = 1.0f / DlB[0];
    float rlC = 1.0f / DlC[0];
    float rlD = 1.0f / DlD[0];
    U8 ByA, ByB, ByC, ByD;
    ByA.u[0] = pack2bf(D0A[0]*rlA, D0A[1]*rlA); ByA.u[1] = pack2bf(D0A[2]*rlA, D0A[3]*rlA);
    ByA.u[2] = pack2bf(D1A[0]*rlA, D1A[1]*rlA); ByA.u[3] = pack2bf(D1A[2]*rlA, D1A[3]*rlA);
    ByB.u[0] = pack2bf(D0B[0]*rlB, D0B[1]*rlB); ByB.u[1] = pack2bf(D0B[2]*rlB, D0B[3]*rlB);
    ByB.u[2] = pack2bf(D1B[0]*rlB, D1B[1]*rlB); ByB.u[3] = pack2bf(D1B[2]*rlB, D1B[3]*rlB);
    ByC.u[0] = pack2bf(D0C[0]*rlC, D0C[1]*rlC); ByC.u[1] = pack2bf(D0C[2]*rlC, D0C[3]*rlC);
    ByC.u[2] = pack2bf(D1C[0]*rlC, D1C[1]*rlC); ByC.u[3] = pack2bf(D1C[2]*rlC, D1C[3]*rlC);
    ByD.u[0] = pack2bf(D0D[0]*rlD, D0D[1]*rlD); ByD.u[1] = pack2bf(D0D[2]*rlD, D0D[3]*rlD);
    ByD.u[2] = pack2bf(D1D[0]*rlD, D1D[1]*rlD); ByD.u[3] = pack2bf(D1D[2]*rlD, D1D[3]*rlD);

    float gam = gamma[0];
    #pragma unroll
    for (int t = 0; t < 4; ++t) {
        int co = t*16 + c15;
        float4 wlo = *(const float4*)(wo + co*32 + quad*4);
        float4 whi = *(const float4*)(wo + co*32 + 16 + quad*4);
        U8 aw;
        aw.u[0] = pack2bf(wlo.x, wlo.y); aw.u[1] = pack2bf(wlo.z, wlo.w);
        aw.u[2] = pack2bf(whi.x, whi.y); aw.u[3] = pack2bf(whi.z, whi.w);
        f32x4 oA = __builtin_amdgcn_mfma_f32_16x16x32_bf16(aw.v, ByA.v, zero4, 0, 0, 0);
        f32x4 oB = __builtin_amdgcn_mfma_f32_16x16x32_bf16(aw.v, ByB.v, zero4, 0, 0, 0);
        f32x4 oC = __builtin_amdgcn_mfma_f32_16x16x32_bf16(aw.v, ByC.v, zero4, 0, 0, 0);
        f32x4 oD = __builtin_amdgcn_mfma_f32_16x16x32_bf16(aw.v, ByD.v, zero4, 0, 0, 0);
        #pragma unroll
        for (int r2 = 0; r2 < 4; ++r2) {
            int co_r = t*16 + quad*4 + r2;
            int base = ((b*CC + co_r) << 14) + q0 + c15;
            out[base]      = x[base]      + gam*oA[r2];
            out[base + 16] = x[base + 16] + gam*oB[r2];
            out[base + 32] = x[base + 32] + gam*oC[r2];
            out[base + 48] = x[base + 48] + gam*oD[r2];
        }
    }
}

// ---------------------------------------------------------------------------
// Workspace: Qb 512K @ 0, Kb 128K @ 524288, Vt 512K @ 655360.
// ---------------------------------------------------------------------------
extern "C" void kernel_launch(void* const* d_in, const int* in_sizes, int n_in,
                              void* d_out, int out_size, void* d_ws, size_t ws_size,
                              hipStream_t stream) {
    const float* x     = (const float*)d_in[0];
    const float* wt    = (const float*)d_in[1];
    const float* wp    = (const float*)d_in[2];
    const float* wg    = (const float*)d_in[3];
    const float* wo    = (const float*)d_in[4];
    const float* gamma = (const float*)d_in[5];
    float* out = (float*)d_out;

    char* ws = (char*)d_ws;
    short* Qb = (short*)(ws);
    short* Kb = (short*)(ws + 524288);
    short* Vt = (short*)(ws + 655360);

    dim3 g1(256, BB, 2);
    proj_kernel<<<g1, 256, 0, stream>>>(x, wt, wp, wg, Qb, Kb, Vt);
    attn_kernel<<<BB*NN/64, 256, 0, stream>>>(Qb, Kb, Vt, x, wo, gamma, out);
}

// Round 10
// 99.680 us; speedup vs baseline: 2.1321x; 1.0085x over previous
//
#include <hip/hip_runtime.h>

#define BB 2
#define CC 64
#define HH 128
#define WW 128
#define NN (HH*WW)          // 16384 queries per batch
#define MM ((HH/2)*(WW/2))  // 4096 keys per batch
#define CV 32
#define LOG2E 1.44269504088896f

typedef __attribute__((ext_vector_type(8))) short bf16x8;
typedef __attribute__((ext_vector_type(4))) float f32x4;
typedef unsigned int uint32;

union U8 { bf16x8 v; uint32 u[4]; };

__device__ __forceinline__ short f2bf(float f) {
    union { float f; unsigned u; } v; v.f = f;
    unsigned u = v.u + 0x7fffu + ((v.u >> 16) & 1u);   // RNE
    return (short)(u >> 16);
}
__device__ __forceinline__ uint32 pack2bf(float lo, float hi) {
    return (uint32)(unsigned short)f2bf(lo) | ((uint32)(unsigned short)f2bf(hi) << 16);
}
// 1-instr truncation pack via v_perm_b32; downward bias cancels in P/l ratio
__device__ __forceinline__ uint32 packperm(float lo, float hi) {
    union { float f; uint32 u; } a, b; a.f = lo; b.f = hi;
    return __builtin_amdgcn_perm(b.u, a.u, 0x07060302u);
}
// async global->LDS DMA, 16B/lane; LDS dst = wave-uniform base + lane*16
__device__ __forceinline__ void gl_lds16(const short* g, short* l) {
    __builtin_amdgcn_global_load_lds(
        (const __attribute__((address_space(1))) void*)g,
        (__attribute__((address_space(3))) void*)l, 16, 0, 0);
}

// ---------------------------------------------------------------------------
// Kernel 1 = R0's proj, byte-exact (XOR-swizzled Vt, matching attn's V LDS
// layout). Measured 4.7us (R4 dup-probe) -- at its floor.
// ---------------------------------------------------------------------------
__global__ __launch_bounds__(256, 4) void proj_kernel(
    const float* __restrict__ x, const float* __restrict__ wt,
    const float* __restrict__ wp, const float* __restrict__ wg,
    short* __restrict__ Qb, short* __restrict__ Kb, short* __restrict__ Vt)
{
    __shared__ float plds[8192];
    __shared__ float phi_lds[512];
    int tid = threadIdx.x;
    int px = tid & 63, part = tid >> 6;
    int sb = blockIdx.x >> 2, cq = blockIdx.x & 3;
    int b = blockIdx.y, z = blockIdx.z;
    int row = px >> 5, col = cq*32 + (px & 31);
    int n = (2*sb + row)*WW + col;
    int wbase = __builtin_amdgcn_readfirstlane(part*16);

    float xv[16];
    #pragma unroll
    for (int i = 0; i < 16; ++i)
        xv[i] = x[((b*CC + part*16 + i) << 14) + n];

    if (z == 0) {
        float po[16];
        #pragma unroll
        for (int o = 0; o < 8; ++o) {
            float a = 0.f;
            #pragma unroll
            for (int i = 0; i < 16; ++i) a += wt[o*64 + wbase + i]*xv[i];
            po[o] = a;
        }
        #pragma unroll
        for (int o = 0; o < 8; ++o) {
            float a = 0.f;
            #pragma unroll
            for (int i = 0; i < 16; ++i) a += wp[o*64 + wbase + i]*xv[i];
            po[8+o] = a;
        }
        #pragma unroll
        for (int o = 0; o < 16; ++o) plds[(o*4 + part)*64 + px] = po[o];
        __syncthreads();
        int og = tid >> 6;
        float sm[4];
        #pragma unroll
        for (int j = 0; j < 4; ++j) {
            int o = og*4 + j;
            sm[j] = (plds[(o*4+0)*64+px] + plds[(o*4+1)*64+px])
                  + (plds[(o*4+2)*64+px] + plds[(o*4+3)*64+px]);
        }
        if (og < 2) {
            uint2 val;
            val.x = pack2bf(sm[0]*LOG2E, sm[1]*LOG2E);
            val.y = pack2bf(sm[2]*LOG2E, sm[3]*LOG2E);
            ((uint2*)Qb)[(b*NN + n)*2 + og] = val;
        } else {
            #pragma unroll
            for (int j = 0; j < 4; ++j)
                phi_lds[((og-2)*4 + j)*64 + px] = sm[j];
        }
        __syncthreads();
        if (tid < 128) {
            int mm = tid & 15, ch = tid >> 4;
            int p00 = 2*mm, p01 = p00+1, p10 = 32+2*mm, p11 = p10+1;
            float mx = fmaxf(fmaxf(phi_lds[ch*64+p00], phi_lds[ch*64+p01]),
                             fmaxf(phi_lds[ch*64+p10], phi_lds[ch*64+p11]));
            int m = sb*64 + cq*16 + mm;
            Kb[(b*MM + m)*8 + ch] = f2bf(mx);
        }
    } else {
        float po[32];
        #pragma unroll
        for (int o = 0; o < 32; ++o) {
            float a = 0.f;
            #pragma unroll
            for (int i = 0; i < 16; ++i) a += wg[o*64 + wbase + i]*xv[i];
            po[o] = a;
        }
        #pragma unroll
        for (int o = 0; o < 32; ++o) plds[(o*4 + part)*64 + px] = po[o];
        __syncthreads();
        int og = tid >> 6;
        float sm[8];
        #pragma unroll
        for (int j = 0; j < 8; ++j) {
            int o = og*8 + j;
            sm[j] = (plds[(o*4+0)*64+px] + plds[(o*4+1)*64+px])
                  + (plds[(o*4+2)*64+px] + plds[(o*4+3)*64+px]);
        }
        __syncthreads();
        #pragma unroll
        for (int j = 0; j < 8; ++j)
            plds[(og*8 + j)*64 + px] = sm[j];
        __syncthreads();
        int mm = tid & 15, chb = tid >> 4;
        int p00 = 2*mm, p01 = p00+1, p10 = 32+2*mm, p11 = p10+1;
        int w64 = cq*16 + mm;
        int hh = w64 >> 5, w = w64 & 31;
        int slot = ((w >> 2) & 3)*8 + (w & 3) + ((w >> 4) << 2);
        int pos64 = hh*32 + slot;
        #pragma unroll
        for (int j = 0; j < 2; ++j) {
            int ch = chb*2 + j;
            float mx = fmaxf(fmaxf(plds[ch*64+p00], plds[ch*64+p01]),
                             fmaxf(plds[ch*64+p10], plds[ch*64+p11]));
            int colv = (pos64 >> 3) ^ (ch & 7);
            Vt[(b*CV + ch)*MM + sb*64 + colv*8 + (pos64 & 7)] = f2bf(mx);
        }
    }
}

// ---------------------------------------------------------------------------
// Kernel 2 = R6's barrier-free attn restructured as an explicit 1-unit
// SOFTWARE PIPELINE (T15 mechanism): per 32-key unit t, do
//   ds_read + QK(t)   [MFMA + LDS stream]
//   exp2/pack/PV(t-1) [trans + VALU stream, register-only]
// The two streams are independent -> the scheduler fills QK's lgkm/MFMA
// latency with exp2 issue (and register-only exp2 may hoist above the vmcnt
// wait). sched_barrier(0) REMOVED (the "memory"-clobber vmcnt asm already
// orders all memory ops; rule #18 doesn't apply -- ds_reads are
// compiler-tracked). DMA schedule/counts byte-identical to R6 (vmcnt(5)
// 1-ahead, vmcnt(0) tail). Arithmetic per unit byte-identical to R6.
// VGPR ~110 (prev-scores 16 + prev-V 8 over R6's 64) -- still <=128, same
// 4 blocks/CU LDS-capped occupancy.
// ---------------------------------------------------------------------------
__global__ __launch_bounds__(256, 4) void attn_kernel(
    const short* __restrict__ Qb, const short* __restrict__ Kb,
    const short* __restrict__ Vt, const float* __restrict__ x,
    const float* __restrict__ wo, const float* __restrict__ gamma,
    float* __restrict__ out)
{
    __shared__ short ldsK[2][4][512];    // 8KB  [buf][wave][64key x 8ch]
    __shared__ short ldsV[2][4][2048];   // 32KB [buf][wave][32ch x 64key swz]
    int tid = threadIdx.x;
    int qtr = tid >> 6, lane = tid & 63;
    int quad = lane >> 4, c15 = lane & 15, sw = c15 & 7;
    int blk = blockIdx.x;
    int b = blk >> 9;
    int q0 = (blk & 511)*32;             // tiles q0, q0+16

    const f32x4 zero4 = {0.f, 0.f, 0.f, 0.f};
    bf16x8 zero8 = (bf16x8)0;
    U8 ones; ones.u[0] = ones.u[1] = ones.u[2] = ones.u[3] = 0x3F803F80u;

    bf16x8 bq0 = (quad == 0) ? ((const bf16x8*)Qb)[b*NN + q0 + c15]      : zero8;
    bf16x8 bq1 = (quad == 0) ? ((const bf16x8*)Qb)[b*NN + q0 + 16 + c15] : zero8;

    // per-wave private DMA sources (this wave's 1024-key quarter, ALL 32 ch)
    const short* ksrc  = Kb + (size_t)b*MM*8 + (qtr*1024 + lane)*8;
    const short* vsrcA = Vt + ((size_t)(b*CV + (lane >> 3)))*MM
                       + qtr*1024 + (lane & 7)*8;       // ch 0..7
    const short* vsrcB = vsrcA + 8*MM;                  // ch 8..15
    const short* vsrcC = vsrcA + 16*MM;                 // ch 16..23
    const short* vsrcD = vsrcA + 24*MM;                 // ch 24..31
    short* kd0 = &ldsK[0][qtr][lane*8];
    short* kd1 = &ldsK[1][qtr][lane*8];
    short* vd0 = &ldsV[0][qtr][lane*8];
    short* vd1 = &ldsV[1][qtr][lane*8];

    // prologue: DMA stage 0 AND stage 1 (10 outstanding), wait for stage 0
    gl_lds16(vsrcA, vd0);       gl_lds16(vsrcB, vd0 + 512);
    gl_lds16(vsrcC, vd0 + 1024); gl_lds16(vsrcD, vd0 + 1536);
    gl_lds16(ksrc, kd0);
    gl_lds16(vsrcA + 64, vd1);       gl_lds16(vsrcB + 64, vd1 + 512);
    gl_lds16(vsrcC + 64, vd1 + 1024); gl_lds16(vsrcD + 64, vd1 + 1536);
    gl_lds16(ksrc + 512, kd1);
    asm volatile("s_waitcnt vmcnt(5)" ::: "memory");

    f32x4 D0A = zero4, D1A = zero4, DlA = zero4;
    f32x4 D0B = zero4, D1B = zero4, DlB = zero4;

    // pipeline registers: prev unit's QK scores + V fragments
    f32x4 pA0, pA1, pB0, pB1;
    bf16x8 pa0, pa1;

    // LOADQK(h): ds_read kf/a for unit (current buf, h) and QK -> cur regs
#define LOADQK(bk, bv, H, cA0, cA1, cB0, cB1, ca0, ca1)                         \
    bf16x8 kf0_##H = *(const bf16x8*)((bk) + ((H)*32 + c15)*8);                 \
    bf16x8 kf1_##H = *(const bf16x8*)((bk) + ((H)*32 + 16 + c15)*8);            \
    bf16x8 ca0 = *(const bf16x8*)((bv) + c15*64 + (((H)*4 + quad) ^ sw)*8);     \
    bf16x8 ca1 = *(const bf16x8*)((bv) + (16 + c15)*64 + (((H)*4 + quad) ^ sw)*8);\
    f32x4 cA0 = __builtin_amdgcn_mfma_f32_16x16x32_bf16(kf0_##H, bq0, zero4, 0, 0, 0); \
    f32x4 cA1 = __builtin_amdgcn_mfma_f32_16x16x32_bf16(kf1_##H, bq0, zero4, 0, 0, 0); \
    f32x4 cB0 = __builtin_amdgcn_mfma_f32_16x16x32_bf16(kf0_##H, bq1, zero4, 0, 0, 0); \
    f32x4 cB1 = __builtin_amdgcn_mfma_f32_16x16x32_bf16(kf1_##H, bq1, zero4, 0, 0, 0);

    // SMPV: softmax+PV of the PREV unit (register-only)
#define SMPV()                                                                  \
    {                                                                           \
        U8 bpA, bpB;                                                            \
        bpA.u[0] = packperm(__builtin_amdgcn_exp2f(pA0[0]), __builtin_amdgcn_exp2f(pA0[1])); \
        bpA.u[1] = packperm(__builtin_amdgcn_exp2f(pA0[2]), __builtin_amdgcn_exp2f(pA0[3])); \
        bpA.u[2] = packperm(__builtin_amdgcn_exp2f(pA1[0]), __builtin_amdgcn_exp2f(pA1[1])); \
        bpA.u[3] = packperm(__builtin_amdgcn_exp2f(pA1[2]), __builtin_amdgcn_exp2f(pA1[3])); \
        bpB.u[0] = packperm(__builtin_amdgcn_exp2f(pB0[0]), __builtin_amdgcn_exp2f(pB0[1])); \
        bpB.u[1] = packperm(__builtin_amdgcn_exp2f(pB0[2]), __builtin_amdgcn_exp2f(pB0[3])); \
        bpB.u[2] = packperm(__builtin_amdgcn_exp2f(pB1[0]), __builtin_amdgcn_exp2f(pB1[1])); \
        bpB.u[3] = packperm(__builtin_amdgcn_exp2f(pB1[2]), __builtin_amdgcn_exp2f(pB1[3])); \
        D0A = __builtin_amdgcn_mfma_f32_16x16x32_bf16(pa0, bpA.v, D0A, 0, 0, 0);\
        D1A = __builtin_amdgcn_mfma_f32_16x16x32_bf16(pa1, bpA.v, D1A, 0, 0, 0);\
        DlA = __builtin_amdgcn_mfma_f32_16x16x32_bf16(ones.v, bpA.v, DlA, 0, 0, 0);\
        D0B = __builtin_amdgcn_mfma_f32_16x16x32_bf16(pa0, bpB.v, D0B, 0, 0, 0);\
        D1B = __builtin_amdgcn_mfma_f32_16x16x32_bf16(pa1, bpB.v, D1B, 0, 0, 0);\
        DlB = __builtin_amdgcn_mfma_f32_16x16x32_bf16(ones.v, bpB.v, DlB, 0, 0, 0);\
    }

#define ROT(cA0, cA1, cB0, cB1, ca0, ca1)                                       \
    pA0 = cA0; pA1 = cA1; pB0 = cB0; pB1 = cB1; pa0 = ca0; pa1 = ca1;

    {   // stage 0, unit h=0: QK only (fills the pipeline)
        const short* bk = &ldsK[0][qtr][0];
        const short* bv = &ldsV[0][qtr][0];
        LOADQK(bk, bv, 0, xA0, xA1, xB0, xB1, xa0, xa1)
        ROT(xA0, xA1, xB0, xB1, xa0, xa1)
        // stage 0, unit h=1: QK(0,1) + SMPV(0,0)
        LOADQK(bk, bv, 1, yA0, yA1, yB0, yB1, ya0, ya1)
        SMPV()
        ROT(yA0, yA1, yB0, yB1, ya0, ya1)
    }

    #pragma unroll 2
    for (int sc = 1; sc < 15; ++sc) {
        int scn = sc + 1;
        short* vd = (scn & 1) ? vd1 : vd0;
        short* kd = (scn & 1) ? kd1 : kd0;
        gl_lds16(vsrcA + scn*64, vd);
        gl_lds16(vsrcB + scn*64, vd + 512);
        gl_lds16(vsrcC + scn*64, vd + 1024);
        gl_lds16(vsrcD + scn*64, vd + 1536);
        gl_lds16(ksrc + scn*512, kd);
        // outstanding: 5(sc) + 5(sc+1); wait until 5 remain -> stage sc landed
        asm volatile("s_waitcnt vmcnt(5)" ::: "memory");

        const short* bk = (sc & 1) ? &ldsK[1][qtr][0] : &ldsK[0][qtr][0];
        const short* bv = (sc & 1) ? &ldsV[1][qtr][0] : &ldsV[0][qtr][0];
        {
            LOADQK(bk, bv, 0, xA0, xA1, xB0, xB1, xa0, xa1)
            SMPV()
            ROT(xA0, xA1, xB0, xB1, xa0, xa1)
        }
        {
            LOADQK(bk, bv, 1, yA0, yA1, yB0, yB1, ya0, ya1)
            SMPV()
            ROT(yA0, yA1, yB0, yB1, ya0, ya1)
        }
    }

    {   // stage 15: no more DMA; drain, then last two units + epilogue
        asm volatile("s_waitcnt vmcnt(0)" ::: "memory");
        const short* bk = &ldsK[1][qtr][0];
        const short* bv = &ldsV[1][qtr][0];
        {
            LOADQK(bk, bv, 0, xA0, xA1, xB0, xB1, xa0, xa1)
            SMPV()
            ROT(xA0, xA1, xB0, xB1, xa0, xa1)
        }
        {
            LOADQK(bk, bv, 1, yA0, yA1, yB0, yB1, ya0, ya1)
            SMPV()
            ROT(yA0, yA1, yB0, yB1, ya0, ya1)
        }
        SMPV()   // flush final unit
    }
#undef LOADQK
#undef SMPV
#undef ROT

    // combine 4 quarter partials; comb aliased onto the writing wave's OWN
    // (drained) ldsV regions: tile A -> ldsV[0][r], tile B -> ldsV[1][r].
    #pragma unroll
    for (int r = 1; r < 4; ++r) {
        if (qtr == r) {
            float* cA = (float*)&ldsV[0][r][0] + lane*9;
            cA[0]=D0A[0]; cA[1]=D0A[1]; cA[2]=D0A[2]; cA[3]=D0A[3];
            cA[4]=D1A[0]; cA[5]=D1A[1]; cA[6]=D1A[2]; cA[7]=D1A[3];
            cA[8]=DlA[0];
            float* cB = (float*)&ldsV[1][r][0] + lane*9;
            cB[0]=D0B[0]; cB[1]=D0B[1]; cB[2]=D0B[2]; cB[3]=D0B[3];
            cB[4]=D1B[0]; cB[5]=D1B[1]; cB[6]=D1B[2]; cB[7]=D1B[3];
            cB[8]=DlB[0];
        }
        __syncthreads();
        if (qtr == 0) {
            const float* cA = (const float*)&ldsV[0][r][0] + lane*9;
            D0A[0]+=cA[0]; D0A[1]+=cA[1]; D0A[2]+=cA[2]; D0A[3]+=cA[3];
            D1A[0]+=cA[4]; D1A[1]+=cA[5]; D1A[2]+=cA[6]; D1A[3]+=cA[7];
            DlA[0]+=cA[8];
            const float* cB = (const float*)&ldsV[1][r][0] + lane*9;
            D0B[0]+=cB[0]; D0B[1]+=cB[1]; D0B[2]+=cB[2]; D0B[3]+=cB[3];
            D1B[0]+=cB[4]; D1B[1]+=cB[5]; D1B[2]+=cB[6]; D1B[3]+=cB[7];
            DlB[0]+=cB[8];
        }
        __syncthreads();
    }
    if (qtr != 0) return;       // no barriers past this point

    float rlA = 1.0f / DlA[0];
    float rlB = 1.0f / DlB[0];
    U8 ByA, ByB;
    ByA.u[0] = pack2bf(D0A[0]*rlA, D0A[1]*rlA); ByA.u[1] = pack2bf(D0A[2]*rlA, D0A[3]*rlA);
    ByA.u[2] = pack2bf(D1A[0]*rlA, D1A[1]*rlA); ByA.u[3] = pack2bf(D1A[2]*rlA, D1A[3]*rlA);
    ByB.u[0] = pack2bf(D0B[0]*rlB, D0B[1]*rlB); ByB.u[1] = pack2bf(D0B[2]*rlB, D0B[3]*rlB);
    ByB.u[2] = pack2bf(D1B[0]*rlB, D1B[1]*rlB); ByB.u[3] = pack2bf(D1B[2]*rlB, D1B[3]*rlB);

    float gam = gamma[0];
    #pragma unroll
    for (int t = 0; t < 4; ++t) {
        int co = t*16 + c15;
        float4 wlo = *(const float4*)(wo + co*32 + quad*4);
        float4 whi = *(const float4*)(wo + co*32 + 16 + quad*4);
        U8 aw;
        aw.u[0] = pack2bf(wlo.x, wlo.y); aw.u[1] = pack2bf(wlo.z, wlo.w);
        aw.u[2] = pack2bf(whi.x, whi.y); aw.u[3] = pack2bf(whi.z, whi.w);
        f32x4 oA = __builtin_amdgcn_mfma_f32_16x16x32_bf16(aw.v, ByA.v, zero4, 0, 0, 0);
        f32x4 oB = __builtin_amdgcn_mfma_f32_16x16x32_bf16(aw.v, ByB.v, zero4, 0, 0, 0);
        #pragma unroll
        for (int r2 = 0; r2 < 4; ++r2) {
            int co_r = t*16 + quad*4 + r2;
            int base = ((b*CC + co_r) << 14) + q0 + c15;
            out[base]      = x[base]      + gam*oA[r2];
            out[base + 16] = x[base + 16] + gam*oB[r2];
        }
    }
}

// ---------------------------------------------------------------------------
// Workspace: Qb 512K @ 0, Kb 128K @ 524288, Vt 512K @ 655360.
// ---------------------------------------------------------------------------
extern "C" void kernel_launch(void* const* d_in, const int* in_sizes, int n_in,
                              void* d_out, int out_size, void* d_ws, size_t ws_size,
                              hipStream_t stream) {
    const float* x     = (const float*)d_in[0];
    const float* wt    = (const float*)d_in[1];
    const float* wp    = (const float*)d_in[2];
    const float* wg    = (const float*)d_in[3];
    const float* wo    = (const float*)d_in[4];
    const float* gamma = (const float*)d_in[5];
    float* out = (float*)d_out;

    char* ws = (char*)d_ws;
    short* Qb = (short*)(ws);
    short* Kb = (short*)(ws + 524288);
    short* Vt = (short*)(ws + 655360);

    dim3 g1(256, BB, 2);
    proj_kernel<<<g1, 256, 0, stream>>>(x, wt, wp, wg, Qb, Kb, Vt);
    attn_kernel<<<BB*NN/32, 256, 0, stream>>>(Qb, Kb, Vt, x, wo, gamma, out);
}